// Round 3
// baseline (128.206 us; speedup 1.0000x reference)
//
#include <hip/hip_runtime.h>
#include <math.h>

constexpr int Bn = 8, Cn = 512, Sn = 256, Mn = 200, Ln = 100;

// workspace layout (in floats)
constexpr size_t OFF_V    = 0;                                 // [B][C][S]
constexpr size_t OFF_VT   = OFF_V   + (size_t)Bn*Cn*Sn;        // [B][S][C]
constexpr size_t OFF_Z    = OFF_VT  + (size_t)Bn*Sn*Cn;        // [B][M][S]
constexpr size_t OFF_ZT   = OFF_Z   + (size_t)Bn*Mn*Sn;        // [B][S][M]
constexpr size_t OFF_INV  = OFF_ZT  + (size_t)Bn*Sn*Mn;        // [B][M]
constexpr size_t OFF_ZW   = OFF_INV + (size_t)Bn*Mn;           // [B][M]
constexpr size_t OFF_ZPW  = OFF_ZW  + (size_t)Bn*Mn;           // [B][M]
constexpr size_t OFF_WSUM = OFF_ZPW + (size_t)Bn*Mn;           // [S]

// ---------- vectorized block reductions (NW = waves per block) ----------
template<int NW>
__device__ __forceinline__ float4 blk_max_f4(float4 x, float4* red) {
  #pragma unroll
  for (int o = 32; o; o >>= 1) {
    x.x = fmaxf(x.x, __shfl_xor(x.x, o));
    x.y = fmaxf(x.y, __shfl_xor(x.y, o));
    x.z = fmaxf(x.z, __shfl_xor(x.z, o));
    x.w = fmaxf(x.w, __shfl_xor(x.w, o));
  }
  __syncthreads();
  if ((threadIdx.x & 63) == 0) red[threadIdx.x >> 6] = x;
  __syncthreads();
  float4 r = red[0];
  #pragma unroll
  for (int w = 1; w < NW; ++w) {
    r.x = fmaxf(r.x, red[w].x); r.y = fmaxf(r.y, red[w].y);
    r.z = fmaxf(r.z, red[w].z); r.w = fmaxf(r.w, red[w].w);
  }
  return r;
}
template<int NW>
__device__ __forceinline__ float4 blk_sum_f4(float4 x, float4* red) {
  #pragma unroll
  for (int o = 32; o; o >>= 1) {
    x.x += __shfl_xor(x.x, o); x.y += __shfl_xor(x.y, o);
    x.z += __shfl_xor(x.z, o); x.w += __shfl_xor(x.w, o);
  }
  __syncthreads();
  if ((threadIdx.x & 63) == 0) red[threadIdx.x >> 6] = x;
  __syncthreads();
  float4 r = red[0];
  #pragma unroll
  for (int w = 1; w < NW; ++w) {
    r.x += red[w].x; r.y += red[w].y; r.z += red[w].z; r.w += red[w].w;
  }
  return r;
}

// ---------- 8x8 block-mean pool (writes v AND vT) + (block 4096) wsum ----------
__global__ void __launch_bounds__(256) k_pool(const float* __restrict__ x,
                                              const float* __restrict__ ow,
                                              float* __restrict__ ws) {
  int t = threadIdx.x;
  if (blockIdx.x == 4096) {                  // wsum[s] = sum_t out_w[s,t]
    const float* row = ow + (size_t)t * Sn;
    float s = 0.f;
    for (int j = 0; j < Sn; j += 4) {
      float4 f = *(const float4*)(row + j);
      s += f.x + f.y + f.z + f.w;
    }
    ws[OFF_WSUM + t] = s;
    return;
  }
  // XCD-chunked swizzle: XCD x owns contiguous bc range [x*512,(x+1)*512)
  int orig = blockIdx.x;
  int bc = (orig & 7) * 512 + (orig >> 3);
  const float* plane = x + (size_t)bc * 16384;
  float part[16];
  #pragma unroll
  for (int i = 0; i < 16; ++i) {
    float4 f = *(const float4*)(plane + i * 1024 + t * 4);
    part[i] = f.x + f.y + f.z + f.w;
  }
  __shared__ float lds[256][17];
  #pragma unroll
  for (int i = 0; i < 16; ++i) lds[t][i] = part[i];
  __syncthreads();
  int i = t >> 4, jj = t & 15;
  float s = 0.f;
  #pragma unroll
  for (int r = 0; r < 8; ++r)
    s += lds[32 * r + 2 * jj][i] + lds[32 * r + 2 * jj + 1][i];
  float val = s * (1.0f / 64.0f);
  ws[OFF_V + (size_t)bc * 256 + t] = val;              // c-major
  int b = bc >> 9, c = bc & 511;
  ws[OFF_VT + ((size_t)b * Sn + t) * Cn + c] = val;    // s-major (scatter)
}

// ---------- fused: t1 = v.psi -> softmax_c -> A(LDS) -> z = A.v, ||z||, z.wsum ----------
__global__ void __launch_bounds__(512) k_psz(const float* __restrict__ psi,
                                             float* __restrict__ ws) {
  int b = blockIdx.y, g = blockIdx.x, t = threadIdx.x;
  int m0 = g * 4;
  __shared__ __align__(16) float pc[4][256];       // psi columns
  __shared__ __align__(16) float As[4][512];       // softmaxed affinity
  __shared__ __align__(16) float zpart[2][4][256];
  __shared__ float4 red4[8];
  const float* v  = ws + OFF_V  + (size_t)b * Cn * Sn;
  const float* vT = ws + OFF_VT + (size_t)b * Sn * Cn;

  for (int e = t; e < 4 * 256; e += 512) {
    int mm = e >> 8, s = e & 255;
    int m = m0 + mm, k = m / Ln, d = m % Ln;
    pc[mm][s] = psi[(size_t)k * Sn * Ln + (size_t)s * Ln + d];
  }
  __syncthreads();

  // phase 1: thread t owns channel c = t ; coalesced vT reads
  float acc[4] = {0, 0, 0, 0};
  for (int s = 0; s < Sn; s += 4) {
    float v0 = vT[(size_t)(s + 0) * Cn + t];
    float v1 = vT[(size_t)(s + 1) * Cn + t];
    float v2 = vT[(size_t)(s + 2) * Cn + t];
    float v3 = vT[(size_t)(s + 3) * Cn + t];
    #pragma unroll
    for (int mm = 0; mm < 4; ++mm) {
      float4 p = *(const float4*)&pc[mm][s];
      acc[mm] += v0 * p.x + v1 * p.y + v2 * p.z + v3 * p.w;
    }
  }
  {
    float4 a = make_float4(acc[0], acc[1], acc[2], acc[3]);
    float4 mx = blk_max_f4<8>(a, red4);
    float4 e;
    e.x = expf(a.x - mx.x); e.y = expf(a.y - mx.y);
    e.z = expf(a.z - mx.z); e.w = expf(a.w - mx.w);
    float4 se = blk_sum_f4<8>(e, red4);
    As[0][t] = e.x / se.x;
    As[1][t] = e.y / se.y;
    As[2][t] = e.z / se.z;
    As[3][t] = e.w / se.w;
  }
  __syncthreads();

  // phase 2: z[m, s2] ; thread = (h = c-half, s2) ; coalesced v reads
  int h = t >> 8, s2 = t & 255;
  float a2[4] = {0, 0, 0, 0};
  const float* vb = v + (size_t)h * 256 * Sn;
  for (int c = 0; c < 256; c += 4) {
    float w0 = vb[(size_t)(c + 0) * Sn + s2];
    float w1 = vb[(size_t)(c + 1) * Sn + s2];
    float w2 = vb[(size_t)(c + 2) * Sn + s2];
    float w3 = vb[(size_t)(c + 3) * Sn + s2];
    #pragma unroll
    for (int mm = 0; mm < 4; ++mm) {
      float4 aa = *(const float4*)&As[mm][h * 256 + c];
      a2[mm] += aa.x * w0 + aa.y * w1 + aa.z * w2 + aa.w * w3;
    }
  }
  #pragma unroll
  for (int mm = 0; mm < 4; ++mm) zpart[h][mm][s2] = a2[mm];
  __syncthreads();

  float zv[4] = {0, 0, 0, 0};
  float wsv = 0.f;
  if (t < 256) {
    wsv = ws[OFF_WSUM + t];
    float* zo = ws + OFF_Z + ((size_t)b * Mn + m0) * Sn;
    #pragma unroll
    for (int mm = 0; mm < 4; ++mm) {
      zv[mm] = zpart[0][mm][t] + zpart[1][mm][t];
      zo[(size_t)mm * Sn + t] = zv[mm];
    }
    // zT scatter: one aligned float4 per thread (m0 % 4 == 0)
    *(float4*)&ws[OFF_ZT + ((size_t)b * Sn + t) * Mn + m0] =
        make_float4(zv[0], zv[1], zv[2], zv[3]);
  }
  float4 n2 = blk_sum_f4<8>(make_float4(zv[0]*zv[0], zv[1]*zv[1],
                                        zv[2]*zv[2], zv[3]*zv[3]), red4);
  float4 zw = blk_sum_f4<8>(make_float4(zv[0]*wsv, zv[1]*wsv,
                                        zv[2]*wsv, zv[3]*wsv), red4);
  if (t == 0) {
    float* inv = ws + OFF_INV + (size_t)b * Mn + m0;
    float* zwp = ws + OFF_ZW  + (size_t)b * Mn + m0;
    inv[0] = 1.0f / (sqrtf(n2.x) + 1e-6f); zwp[0] = zw.x;
    inv[1] = 1.0f / (sqrtf(n2.y) + 1e-6f); zwp[1] = zw.y;
    inv[2] = 1.0f / (sqrtf(n2.z) + 1e-6f); zwp[2] = zw.z;
    inv[3] = 1.0f / (sqrtf(n2.w) + 1e-6f); zwp[3] = zw.w;
  }
}

// ---------- G = softmax_n(zn.zn); zp_w[m] = sum_n G[m,n] zw[n] ----------
__global__ void __launch_bounds__(256) k_g(float* __restrict__ ws) {
  int b = blockIdx.y, g = blockIdx.x, t = threadIdx.x;
  int m0 = g * 2;
  __shared__ __align__(16) float zl[2][256];
  __shared__ float invl[200], zwl[200];
  __shared__ float4 red4[4];
  const float* z  = ws + OFF_Z  + (size_t)b * Mn * Sn;
  const float* zT = ws + OFF_ZT + (size_t)b * Sn * Mn;
  zl[0][t] = z[(size_t)(m0 + 0) * Sn + t];
  zl[1][t] = z[(size_t)(m0 + 1) * Sn + t];
  if (t < Mn) {
    invl[t] = ws[OFF_INV + (size_t)b * Mn + t];
    zwl[t]  = ws[OFF_ZW  + (size_t)b * Mn + t];
  }
  __syncthreads();
  bool act = t < Mn;
  float d0 = 0.f, d1 = 0.f;
  if (act) {
    // thread t owns column n = t ; coalesced zT reads
    for (int s = 0; s < Sn; s += 4) {
      float z0 = zT[(size_t)(s + 0) * Mn + t];
      float z1 = zT[(size_t)(s + 1) * Mn + t];
      float z2 = zT[(size_t)(s + 2) * Mn + t];
      float z3 = zT[(size_t)(s + 3) * Mn + t];
      d0 += z0 * zl[0][s] + z1 * zl[0][s+1] + z2 * zl[0][s+2] + z3 * zl[0][s+3];
      d1 += z0 * zl[1][s] + z1 * zl[1][s+1] + z2 * zl[1][s+2] + z3 * zl[1][s+3];
    }
  }
  float4 val;
  val.x = act ? d0 * invl[m0 + 0] * invl[t] : -1e30f;
  val.y = act ? d1 * invl[m0 + 1] * invl[t] : -1e30f;
  val.z = -1e30f; val.w = -1e30f;
  float4 mx = blk_max_f4<4>(val, red4);
  float ex = act ? expf(val.x - mx.x) : 0.f;
  float ey = act ? expf(val.y - mx.y) : 0.f;
  float4 se = blk_sum_f4<4>(make_float4(ex, ey, 0.f, 0.f), red4);
  float zwn = act ? zwl[t] : 0.f;
  float4 sez = blk_sum_f4<4>(make_float4(ex * zwn, ey * zwn, 0.f, 0.f), red4);
  if (t == 0) {
    float* zp = ws + OFF_ZPW + (size_t)b * Mn + m0;
    zp[0] = sez.x / se.x;
    zp[1] = sez.y / se.y;
  }
}

// ---------- t2 = v.phi, softmax over d, dot zp_w, + vsum, sigmoid ----------
__global__ void __launch_bounds__(256) k_out(const float* __restrict__ phi,
                                             float* __restrict__ out,
                                             float* __restrict__ ws) {
  int b = blockIdx.y, cg = blockIdx.x, t = threadIdx.x;
  int c0 = cg * 4;
  __shared__ __align__(16) float vl[4][256];
  __shared__ float zpl[200];
  __shared__ float t2l[8][104];
  __shared__ float resl[2][4];
  __shared__ float vsl[4];
  const float* v = ws + OFF_V + ((size_t)b * Cn + c0) * Sn;
  #pragma unroll
  for (int cc = 0; cc < 4; ++cc) vl[cc][t] = v[(size_t)cc * Sn + t];
  if (t < Mn) zpl[t] = ws[OFF_ZPW + (size_t)b * Mn + t];
  __syncthreads();
  int k = t >> 7, d = t & 127;
  int dd = d < Ln ? d : Ln - 1;
  const float* pp = phi + (size_t)k * Sn * Ln + dd;
  float acc[4] = {0, 0, 0, 0};
  for (int s = 0; s < Sn; s += 4) {
    float p0 = pp[(size_t)(s + 0) * Ln];
    float p1 = pp[(size_t)(s + 1) * Ln];
    float p2 = pp[(size_t)(s + 2) * Ln];
    float p3 = pp[(size_t)(s + 3) * Ln];
    #pragma unroll
    for (int cc = 0; cc < 4; ++cc) {
      float4 vv = *(const float4*)&vl[cc][s];
      acc[cc] += vv.x * p0 + vv.y * p1 + vv.z * p2 + vv.w * p3;
    }
  }
  if (d < Ln) {
    #pragma unroll
    for (int cc = 0; cc < 4; ++cc) t2l[k * 4 + cc][d] = acc[cc];
  }
  __syncthreads();
  // 8 groups of 32 lanes; group gg = k2*4+cc2 reduces over d (100 entries)
  int gg = t >> 5, l = t & 31;
  int k2 = gg >> 2, cc2 = gg & 3;
  float mx = -1e30f;
  for (int dq = l; dq < Ln; dq += 32) mx = fmaxf(mx, t2l[gg][dq]);
  #pragma unroll
  for (int o = 16; o; o >>= 1) mx = fmaxf(mx, __shfl_xor(mx, o));
  float se = 0.f, sez = 0.f;
  for (int dq = l; dq < Ln; dq += 32) {
    float e = expf(t2l[gg][dq] - mx);
    se += e;
    sez += e * zpl[k2 * Ln + dq];
  }
  #pragma unroll
  for (int o = 16; o; o >>= 1) { se += __shfl_xor(se, o); sez += __shfl_xor(sez, o); }
  float vs = 0.f;
  if (k2 == 0) {                              // k=0 groups also compute vsum[cc]
    for (int i2 = 0; i2 < 8; ++i2) vs += vl[cc2][i2 * 32 + l];
    #pragma unroll
    for (int o = 16; o; o >>= 1) vs += __shfl_xor(vs, o);
    if (l == 0) vsl[cc2] = vs;
  }
  if (l == 0) resl[k2][cc2] = sez / se;
  __syncthreads();
  if (t < 4) {
    float f = (vsl[t] + resl[0][t] + resl[1][t]) * (1.0f / 256.0f);
    out[(size_t)b * Cn + c0 + t] = 1.0f / (1.0f + expf(-f));
  }
}

extern "C" void kernel_launch(void* const* d_in, const int* in_sizes, int n_in,
                              void* d_out, int out_size, void* d_ws, size_t ws_size,
                              hipStream_t stream) {
  const float* x   = (const float*)d_in[0];
  const float* psi = (const float*)d_in[1];
  const float* phi = (const float*)d_in[2];
  const float* ow  = (const float*)d_in[3];
  float* out = (float*)d_out;
  float* ws  = (float*)d_ws;

  hipLaunchKernelGGL(k_pool, dim3(4097),    dim3(256), 0, stream, x, ow, ws);
  hipLaunchKernelGGL(k_psz,  dim3(50, 8),   dim3(512), 0, stream, psi, ws);
  hipLaunchKernelGGL(k_g,    dim3(100, 8),  dim3(256), 0, stream, ws);
  hipLaunchKernelGGL(k_out,  dim3(128, 8),  dim3(256), 0, stream, phi, out, ws);
}